// Round 5
// baseline (2264.332 us; speedup 1.0000x reference)
//
#include <hip/hip_runtime.h>
#include <cstdint>
#include <cstddef>

// ---------------------------------------------------------------------------
// GraphCNN on MI355X (gfx950).
//   x = mlp3_h(node_inputs)
//   8x { t1 = mlp3_f(x); t2 = segsum(adj * t1[dst], src); x += mask * mlp3_f(t2) }
// GEMMs: fp32 emulated via f16 hi/lo split, 3x v_mfma_f32_16x16x32_f16
//   (dropped xl*wl term ~2^-22 rel; fp32-class accuracy).
// mlp3 kernel: 512 thr (8 waves, wave w owns n-col 16-slices, all m-tiles).
//   Blocks: 53x80 rows + 715x64 rows = 50000 exactly, 768 = 3*256 blocks
//   (no round quantization, big blocks first).
//   Weights stream global->LDS in 16KB segments, TRIPLE buffered, one barrier
//   per segment, counted vmcnt(2) (never drained mid-loop), 2-segment lead.
//   A-fragments double-buffered in registers, prefetched chunk-ahead.
//   Activations in LDS as packed (f16hi | f16lo<<16) u32, 16B XOR swizzle.
// MODE 1 fuses the segment-sum: per-block wave-per-node CSR gather of
//   adj*t1[dst] directly into activation LDS (no t2 round-trip, no seg_k).
// Sparse: CSR built per-launch (hist + 3-phase scan + fill {val,dst} pairs in
//   CSR order). Workspace tiers by ws_size: full (97MB, all-depth CSR) /
//   mid (57.9MB, per-depth CSR) / tiny (32.3MB, t1 aliased to d_out + final
//   D2D copy).
// ---------------------------------------------------------------------------

#define NNODES 50000
#define NEDGES 600000
#define NDEPTH 8

typedef _Float16 half8 __attribute__((ext_vector_type(8)));
typedef float f32x4 __attribute__((ext_vector_type(4)));

constexpr int NB5 = 53;                   // 80-row blocks (first, LPT order)
constexpr int NB4 = 715;                  // 64-row blocks
constexpr int GRID_MLP = NB5 + NB4;       // 768 = 3 * 256

constexpr int ACT_BYTES = 81920;          // 80 rows x 256 u32
constexpr int WB_BYTES = 3 * 16384;       // weight triple buffer
constexpr int SMEM_TOTAL = ACT_BYTES + WB_BYTES;   // 131072 = 128 KiB

// f16-element offsets of the 3 matrices inside one weight-set fragment blob
constexpr int WOFF2 = 128 * 256 * 2;             // 65536
constexpr int WOFF3 = WOFF2 + 256 * 256 * 2;     // 196608
constexpr int WSET  = WOFF3 + 256 * 128 * 2;     // 262144 f16 = 512KB

// ---------------- helpers ----------------

__device__ __forceinline__ unsigned int packf(float x) {
  _Float16 h = (_Float16)x;
  float hf = (float)h;
  _Float16 l = (_Float16)(x - hf);
  unsigned short uh = __builtin_bit_cast(unsigned short, h);
  unsigned short ul = __builtin_bit_cast(unsigned short, l);
  return (unsigned int)uh | ((unsigned int)ul << 16);
}

// Integer-truncation addrspace casts (CK's amd_direct_load pattern).
// AMDGPU lowers local->flat addrspacecast as {aperture_hi, lds_offset}: the
// low 32 bits of a flat LDS address ARE the LDS byte offset, so truncating is
// exact. Global flat == AS1 bit pattern. Avoids C-style pointer casts across
// address spaces (compile-safety: clang/HIP may reject those).
__device__ __forceinline__ void gload_lds16(const void* g, void* l) {
  const __attribute__((address_space(1))) unsigned int* gp =
      (const __attribute__((address_space(1))) unsigned int*)(uintptr_t)g;
  __attribute__((address_space(3))) unsigned int* lp =
      (__attribute__((address_space(3))) unsigned int*)(unsigned int)(uintptr_t)l;
  __builtin_amdgcn_global_load_lds(gp, lp, 16, 0, 0);
}

__device__ __forceinline__ void vmwait2() { asm volatile("s_waitcnt vmcnt(2)" ::: "memory"); }
__device__ __forceinline__ void vmwait0() { asm volatile("s_waitcnt vmcnt(0)" ::: "memory"); }

// stage one 16KB weight segment (16 x 1KB pieces; 2 pieces per wave)
__device__ __forceinline__ void stage_seg(const char* wsrc, char* wbuf, int s,
                                          int lane, int w) {
  const char* g = wsrc + (size_t)s * 16384;
  char* l = wbuf + (s % 3) * 16384;
#pragma unroll
  for (int i = 0; i < 2; ++i) {
    const int p = w + i * 8;
    gload_lds16(g + p * 1024 + lane * 16, l + p * 1024);
  }
}

__device__ __forceinline__ void unpack8(uint4 q0, uint4 q1, half8& h, half8& l) {
  union U { unsigned int u[4]; half8 v; };
  U H, L;
  H.u[0] = (q0.x & 0xffffu) | (q0.y << 16);
  H.u[1] = (q0.z & 0xffffu) | (q0.w << 16);
  H.u[2] = (q1.x & 0xffffu) | (q1.y << 16);
  H.u[3] = (q1.z & 0xffffu) | (q1.w << 16);
  L.u[0] = (q0.x >> 16) | (q0.y & 0xffff0000u);
  L.u[1] = (q0.z >> 16) | (q0.w & 0xffff0000u);
  L.u[2] = (q1.x >> 16) | (q1.y & 0xffff0000u);
  L.u[3] = (q1.z >> 16) | (q1.w & 0xffff0000u);
  h = H.v;
  l = L.v;
}

// act element (row,c) at u32 idx row*256 + (c ^ ((row&7)<<2)); 16B XOR swizzle
__device__ __forceinline__ void read_a(const unsigned int* act, int mt, int t,
                                       int rb, int k0q, half8& h, half8& l) {
  const int row = mt * 16 + rb;
  const int sw = (row & 7) << 2;
  const int c0 = t * 32 + k0q;
  const unsigned int* ap = act + row * 256;
  uint4 q0 = *(const uint4*)(ap + (c0 ^ sw));
  uint4 q1 = *(const uint4*)(ap + ((c0 + 4) ^ sw));
  unpack8(q0, q1, h, l);
}

// ---------------- fused MLP3 building blocks ----------------
// Segment = 16KB = 8 n-tiles (hi+lo) of one K=32 chunk slice.
// NSEG = N/128 segments per chunk. Wave w's n-tile in segment (t,h): u = h*8+w.

template <int K, int N, int MTN>
__device__ __forceinline__ void gemm_layer(const unsigned int* act, char* wbuf,
                                           const char* wsrc, int lane, int w,
                                           f32x4* acc) {
  constexpr int KT = K / 32;
  constexpr int NSEG = N / 128;               // 2 or 1
  constexpr int TOT = KT * NSEG;
  constexpr int M0 = (NSEG == 2) ? (MTN + 1) / 2 : MTN;   // A-prefetch split

  f32x4 zz = {0.f, 0.f, 0.f, 0.f};
#pragma unroll
  for (int i = 0; i < MTN * NSEG; ++i) acc[i] = zz;

  stage_seg(wsrc, wbuf, 0, lane, w);
  stage_seg(wsrc, wbuf, 1, lane, w);

  const int rb = lane & 15;
  const int k0q = (lane >> 4) * 8;

  half8 ah[2][MTN], al[2][MTN];
  // chunk-0 A-fragments, overlapping prologue staging latency (act is ready)
#pragma unroll
  for (int mt = 0; mt < MTN; ++mt)
    read_a(act, mt, 0, rb, k0q, ah[0][mt], al[0][mt]);

#pragma unroll
  for (int s = 0; s < TOT; ++s) {
    const int t = s / NSEG;
    const int h = s % NSEG;
    if (s == TOT - 1) vmwait0(); else vmwait2();    // seg s landed (counted)
    __builtin_amdgcn_s_barrier();                    // also orders seg s-1 reads
    asm volatile("" ::: "memory");
    if (s + 2 < TOT) stage_seg(wsrc, wbuf, s + 2, lane, w);  // overwrites buf (s-1)%3
    // prefetch next chunk's A-fragments, split across this chunk's segments
    if (t + 1 < KT) {
      const int lo = (h == 0) ? 0 : M0;
      const int hi = (h == 0 && NSEG == 2) ? M0 : MTN;
#pragma unroll
      for (int mt = 0; mt < MTN; ++mt)
        if (mt >= lo && mt < hi)
          read_a(act, mt, t + 1, rb, k0q, ah[(t + 1) & 1][mt], al[(t + 1) & 1][mt]);
    }
    const char* cur = wbuf + (s % 3) * 16384;
    half8 bh = *(const half8*)(cur + w * 2048 + lane * 16);
    half8 bl = *(const half8*)(cur + w * 2048 + 1024 + lane * 16);
#pragma unroll
    for (int mt = 0; mt < MTN; ++mt) {
      f32x4 c = acc[mt * NSEG + h];
      c = __builtin_amdgcn_mfma_f32_16x16x32_f16(al[t & 1][mt], bh, c, 0, 0, 0);
      c = __builtin_amdgcn_mfma_f32_16x16x32_f16(ah[t & 1][mt], bl, c, 0, 0, 0);
      c = __builtin_amdgcn_mfma_f32_16x16x32_f16(ah[t & 1][mt], bh, c, 0, 0, 0);
      acc[mt * NSEG + h] = c;
    }
  }
}

template <int MTN>
__device__ __forceinline__ void transition(const f32x4* acc, unsigned int* act,
                                           const float* B, int lane, int w) {
  const int rq = (lane >> 4) * 4;
  __syncthreads();
#pragma unroll
  for (int h = 0; h < 2; ++h) {
    const int col = (h * 8 + w) * 16 + (lane & 15);
    const float bv = B[col];
#pragma unroll
    for (int mt = 0; mt < MTN; ++mt) {
#pragma unroll
      for (int r = 0; r < 4; ++r) {
        const int row = mt * 16 + rq + r;
        float v = acc[mt * 2 + h][r] + bv;
        v = v > 0.f ? v : 0.01f * v;
        act[row * 256 + (col ^ ((row & 7) << 2))] = packf(v);
      }
    }
  }
  __syncthreads();
}

template <int MODE, int MTN>
__device__ __forceinline__ void epilogue(const f32x4* acc, const float* B, float* Y,
                                         const float* ADD, const float* MK,
                                         int row0, int lane, int w) {
  const int rq = (lane >> 4) * 4;
  const int col = w * 16 + (lane & 15);
  const float bv = B[col];
#pragma unroll
  for (int mt = 0; mt < MTN; ++mt) {
#pragma unroll
    for (int r = 0; r < 4; ++r) {
      const int grow = row0 + mt * 16 + rq + r;
      float v = acc[mt][r] + bv;
      v = v > 0.f ? v : 0.01f * v;
      float o = (MODE == 0) ? v : ADD[(size_t)grow * 128 + col] + MK[grow] * v;
      Y[(size_t)grow * 128 + col] = o;
    }
  }
}

// MODE 0: stage X rows [row0, row0+16*MTN) into act.
// MODE 1: X is the gather source (t1); CSR segment-sum straight into act.
template <int MODE, int MTN>
__device__ __forceinline__ void mlp3_body(int row0, const float* X,
    const _Float16* WF, const float* B1, const float* B2, const float* B3,
    float* Y, const float* ADD, const float* MK,
    const int2* pairs, const int* rowptr, char* smem) {
  unsigned int* act = (unsigned int*)smem;
  char* wbuf = smem + ACT_BYTES;
  const int tid = threadIdx.x;
  const int lane = tid & 63;
  const int w = tid >> 6;

  if (MODE == 1) {
    // fused segment-sum: wave per node, lane covers cols {2*lane, 2*lane+1}
#pragma unroll 1
    for (int rr = w; rr < 16 * MTN; rr += 8) {
      const int node = row0 + rr;
      const int p0 = rowptr[node];
      const int p1 = rowptr[node + 1];
      float a0 = 0.f, a1 = 0.f;
      int p = p0;
#pragma unroll 1
      for (; p + 4 <= p1; p += 4) {
        int2 q[4];
        float2 yy[4];
#pragma unroll
        for (int j = 0; j < 4; ++j) q[j] = pairs[p + j];
#pragma unroll
        for (int j = 0; j < 4; ++j)
          yy[j] = *(const float2*)(X + (size_t)q[j].y * 128 + lane * 2);
#pragma unroll
        for (int j = 0; j < 4; ++j) {
          const float v = __int_as_float(q[j].x);
          a0 += v * yy[j].x;
          a1 += v * yy[j].y;
        }
      }
#pragma unroll 1
      for (; p < p1; ++p) {
        const int2 q = pairs[p];
        const float v = __int_as_float(q.x);
        const float2 yy = *(const float2*)(X + (size_t)q.y * 128 + lane * 2);
        a0 += v * yy.x;
        a1 += v * yy.y;
      }
      const int sw = (rr & 7) << 2;
      *(uint2*)(act + rr * 256 + ((2 * lane) ^ sw)) =
          make_uint2(packf(a0), packf(a1));
    }
  } else {
    // stage X (16*MTN rows x 128 f32) into act as packed hi|lo u32, swizzled
#pragma unroll
    for (int i = 0; i < MTN; ++i) {
      const int fi = tid + i * 512;            // float4 index
      const int r = fi >> 5;
      const int c4 = (fi & 31) << 2;
      const float4 v = *(const float4*)(X + (size_t)(row0 + r) * 128 + c4);
      uint4 pv = make_uint4(packf(v.x), packf(v.y), packf(v.z), packf(v.w));
      *(uint4*)(act + r * 256 + (c4 ^ ((r & 7) << 2))) = pv;
    }
  }
  __syncthreads();

  f32x4 acc[2 * MTN];
  gemm_layer<128, 256, MTN>(act, wbuf, (const char*)WF, lane, w, acc);
  transition<MTN>(acc, act, B1, lane, w);
  gemm_layer<256, 256, MTN>(act, wbuf, (const char*)(WF + WOFF2), lane, w, acc);
  transition<MTN>(acc, act, B2, lane, w);
  gemm_layer<256, 128, MTN>(act, wbuf, (const char*)(WF + WOFF3), lane, w, acc);
  epilogue<MODE, MTN>(acc, B3, Y, ADD, MK, row0, lane, w);
}

template <int MODE>
__global__ __launch_bounds__(512, 1) void mlp3_k(
    const float* __restrict__ X, const _Float16* __restrict__ WF,
    const float* __restrict__ B1, const float* __restrict__ B2,
    const float* __restrict__ B3, float* __restrict__ Y,
    const float* __restrict__ ADD, const float* __restrict__ MK,
    const int2* __restrict__ pairs, const int* __restrict__ rowptr) {
  extern __shared__ char smem[];
  const int bid = blockIdx.x;
  if (bid < NB5)
    mlp3_body<MODE, 5>(bid * 80, X, WF, B1, B2, B3, Y, ADD, MK, pairs, rowptr, smem);
  else
    mlp3_body<MODE, 4>(NB5 * 80 + (bid - NB5) * 64, X, WF, B1, B2, B3, Y, ADD, MK,
                       pairs, rowptr, smem);
}

// ---------------- weight prep: fp32 -> f16 hi/lo MFMA fragment layout ----------------
// Per matrix (K x N), chunk ct, n-tile u: [hi 1KB][lo 1KB] at (ct*NT+u)*2048 B;
// piece elem: lane l, j -> W[ct*32 + (l>>4)*8 + j][u*16 + (l&15)].

__global__ void prep_k(const float* __restrict__ W0, const float* __restrict__ W1,
                       const float* __restrict__ W2, const float* __restrict__ W3,
                       const float* __restrict__ W4, const float* __restrict__ W5,
                       _Float16* __restrict__ out) {
  const int t = blockIdx.x * 256 + threadIdx.x;   // 0..32767
  const float* W;
  int N, off, local;
  if (t < 4096)       { W = W0; N = 256; off = 0;               local = t; }
  else if (t < 12288) { W = W1; N = 256; off = WOFF2;           local = t - 4096; }
  else if (t < 16384) { W = W2; N = 128; off = WOFF3;           local = t - 12288; }
  else if (t < 20480) { W = W3; N = 256; off = WSET;            local = t - 16384; }
  else if (t < 28672) { W = W4; N = 256; off = WSET + WOFF2;    local = t - 20480; }
  else                { W = W5; N = 128; off = WSET + WOFF3;    local = t - 28672; }
  const int l = local & 63;
  const int q = local >> 6;
  const int NT = N >> 4;
  const int u = q % NT;
  const int ct = q / NT;
  const int k0 = ct * 32 + ((l >> 4) << 3);
  const int n = (u << 4) + (l & 15);
  half8 h, lo;
#pragma unroll
  for (int j = 0; j < 8; ++j) {
    const float v = W[(size_t)(k0 + j) * N + n];
    _Float16 hi = (_Float16)v;
    h[j] = hi;
    lo[j] = (_Float16)(v - (float)hi);
  }
  _Float16* o = out + off + (size_t)(ct * NT + u) * 1024 + (size_t)l * 8;
  *(half8*)o = h;
  *(half8*)(o + 512) = lo;
}

// ---------------- CSR build (hist + 3-phase scan + fill) ----------------

constexpr int NCHUNK = 196;   // ceil(50000/256)

__global__ void hist_k(const int* __restrict__ src, int* __restrict__ cnt) {
  const int e = blockIdx.x * 256 + threadIdx.x;
  const int d = blockIdx.y;
  if (e < NEDGES) atomicAdd(&cnt[(size_t)d * NNODES + src[(size_t)d * NEDGES + e]], 1);
}

__global__ void scan1_k(const int* __restrict__ cnt, int* __restrict__ tmp,
                        int* __restrict__ csum) {
  const int d = blockIdx.y;
  const int chunk = blockIdx.x;
  const int tid = threadIdx.x;
  const int i = chunk * 256 + tid;
  __shared__ int sd[256];
  const int v = (i < NNODES) ? cnt[(size_t)d * NNODES + i] : 0;
  sd[tid] = v;
  __syncthreads();
  int run = v;
  for (int off = 1; off < 256; off <<= 1) {
    const int t_ = (tid >= off) ? sd[tid - off] : 0;
    __syncthreads();
    run += t_;
    sd[tid] = run;
    __syncthreads();
  }
  if (i < NNODES) tmp[(size_t)d * NNODES + i] = run - v;
  if (tid == 255) csum[d * 256 + chunk] = run;
}

__global__ void scan2_k(int* __restrict__ csum, int* __restrict__ rowptr) {
  const int d = blockIdx.x;
  const int tid = threadIdx.x;
  __shared__ int sd[256];
  const int v = (tid < NCHUNK) ? csum[d * 256 + tid] : 0;
  sd[tid] = v;
  __syncthreads();
  int run = v;
  for (int off = 1; off < 256; off <<= 1) {
    const int t_ = (tid >= off) ? sd[tid - off] : 0;
    __syncthreads();
    run += t_;
    sd[tid] = run;
    __syncthreads();
  }
  csum[d * 256 + tid] = run - v;
  if (tid == 0) rowptr[(size_t)d * (NNODES + 1) + NNODES] = NEDGES;
}

__global__ void scan3_k(const int* __restrict__ tmp, const int* __restrict__ csum,
                        int* __restrict__ rowptr, int* __restrict__ cursor) {
  const int d = blockIdx.y;
  const int i = blockIdx.x * 256 + threadIdx.x;
  if (i < NNODES) {
    const int v = tmp[(size_t)d * NNODES + i] + csum[d * 256 + blockIdx.x];
    rowptr[(size_t)d * (NNODES + 1) + i] = v;
    cursor[(size_t)d * NNODES + i] = v;
  }
}

__global__ void fill_k(const int* __restrict__ src, const int* __restrict__ dst,
                       const float* __restrict__ vals, int* __restrict__ cursor,
                       int2* __restrict__ pairs) {
  const int e = blockIdx.x * 256 + threadIdx.x;
  const int d = blockIdx.y;
  if (e < NEDGES) {
    const size_t be = (size_t)d * NEDGES + e;
    const int s = src[be];
    const int pos = atomicAdd(&cursor[(size_t)d * NNODES + s], 1);
    pairs[(size_t)d * NEDGES + pos] = make_int2(__float_as_int(vals[be]), dst[be]);
  }
}

// ---------------- host launch ----------------

extern "C" void kernel_launch(void* const* d_in, const int* in_sizes, int n_in,
                              void* d_out, int out_size, void* d_ws, size_t ws_size,
                              hipStream_t stream) {
  (void)in_sizes; (void)n_in; (void)out_size;

  const float* node_inputs = (const float*)d_in[0];
  const int* edge_src = (const int*)d_in[1];
  const int* edge_dst = (const int*)d_in[2];
  const float* adj_vals = (const float*)d_in[3];
  const float* masks = (const float*)d_in[4];
  const float* W_h1 = (const float*)d_in[5];
  const float* b_h1 = (const float*)d_in[6];
  const float* W_h2 = (const float*)d_in[7];
  const float* b_h2 = (const float*)d_in[8];
  const float* W_h3 = (const float*)d_in[9];
  const float* b_h3 = (const float*)d_in[10];
  const float* W_f1 = (const float*)d_in[11];
  const float* b_f1 = (const float*)d_in[12];
  const float* W_f2 = (const float*)d_in[13];
  const float* b_f2 = (const float*)d_in[14];
  const float* W_f3 = (const float*)d_in[15];
  const float* b_f3 = (const float*)d_in[16];

  char* ws = (char*)d_ws;
  _Float16* wfrag = (_Float16*)ws;                   // 1,048,576 B (both sets)
  float* x = (float*)(ws + 1048576u);                // 25,600,000 B

  // workspace tiers (ws_size is constant across calls -> graph-safe)
  constexpr size_t CSR_SMALL = 5601032u;             // per-depth CSR block
  constexpr size_t FULL_NEED = 97056800u;
  constexpr size_t MID_NEED  = 52248576u + CSR_SMALL;   // 57,849,608
  const int tier = (ws_size >= FULL_NEED) ? 2 : (ws_size >= MID_NEED) ? 1 : 0;

  // t1: gather source. tiers 1/2: in ws. tier 0: aliased to d_out.
  float* t1 = (tier > 0) ? (float*)(ws + 26648576u) : (float*)d_out;
  const size_t csrb = (tier == 2) ? 52248576u
                    : (tier == 1) ? 52248576u
                                  : 26648576u;

  hipFuncSetAttribute(reinterpret_cast<const void*>(&mlp3_k<0>),
                      hipFuncAttributeMaxDynamicSharedMemorySize, SMEM_TOTAL);
  hipFuncSetAttribute(reinterpret_cast<const void*>(&mlp3_k<1>),
                      hipFuncAttributeMaxDynamicSharedMemorySize, SMEM_TOTAL);

  // weights -> f16 hi/lo fragment layout
  prep_k<<<128, 256, 0, stream>>>(W_h1, W_h2, W_h3, W_f1, W_f2, W_f3, wfrag);

  const _Float16* wh = wfrag;
  const _Float16* wf = wfrag + WSET;

  int* cnt;
  int* tmp;
  int* csum;
  int* rowptr;
  int* cursor;
  int2* pairs;

  if (tier == 2) {
    cnt    = (int*)(ws + csrb);                      // 1,600,000
    tmp    = (int*)(ws + csrb + 1600000u);           // 1,600,000
    csum   = (int*)(ws + csrb + 3200000u);           // 8,192
    rowptr = (int*)(ws + csrb + 3208192u);           // 1,600,032
    cursor = (int*)(ws + csrb + 4808224u);           // 1,600,000
    pairs  = (int2*)(ws + csrb + 6408224u);          // 38,400,000 (end 97,056,800)
    hipMemsetAsync(cnt, 0, (size_t)NDEPTH * NNODES * 4, stream);
    hist_k<<<dim3(2344, NDEPTH), 256, 0, stream>>>(edge_src, cnt);
    scan1_k<<<dim3(NCHUNK, NDEPTH), 256, 0, stream>>>(cnt, tmp, csum);
    scan2_k<<<NDEPTH, 256, 0, stream>>>(csum, rowptr);
    scan3_k<<<dim3(NCHUNK, NDEPTH), 256, 0, stream>>>(tmp, csum, rowptr, cursor);
    fill_k<<<dim3(2344, NDEPTH), 256, 0, stream>>>(edge_src, edge_dst, adj_vals,
                                                   cursor, pairs);
  } else {
    cnt    = (int*)(ws + csrb);                      // 200,000 (per depth)
    tmp    = (int*)(ws + csrb + 200000u);            // 200,000
    csum   = (int*)(ws + csrb + 400000u);            // 1,024
    rowptr = (int*)(ws + csrb + 401024u);            // 200,004
    cursor = (int*)(ws + csrb + 601028u);            // 200,000
    pairs  = (int2*)(ws + csrb + 801032u);           // 4,800,000
  }

  // x = mlp3_h(node_inputs)
  mlp3_k<0><<<GRID_MLP, 512, SMEM_TOTAL, stream>>>(node_inputs, wh, b_h1, b_h2,
                                                   b_h3, x, nullptr, nullptr,
                                                   nullptr, nullptr);

  for (int d = 0; d < NDEPTH; ++d) {
    const int* rp_d;
    const int2* pr_d;
    if (tier == 2) {
      rp_d = rowptr + (size_t)d * (NNODES + 1);
      pr_d = pairs + (size_t)d * NEDGES;
    } else {
      // rebuild CSR for this depth in the small scratch area
      hipMemsetAsync(cnt, 0, (size_t)NNODES * 4, stream);
      hist_k<<<dim3(2344, 1), 256, 0, stream>>>(edge_src + (size_t)d * NEDGES, cnt);
      scan1_k<<<dim3(NCHUNK, 1), 256, 0, stream>>>(cnt, tmp, csum);
      scan2_k<<<1, 256, 0, stream>>>(csum, rowptr);
      scan3_k<<<dim3(NCHUNK, 1), 256, 0, stream>>>(tmp, csum, rowptr, cursor);
      fill_k<<<dim3(2344, 1), 256, 0, stream>>>(edge_src + (size_t)d * NEDGES,
                                                edge_dst + (size_t)d * NEDGES,
                                                adj_vals + (size_t)d * NEDGES,
                                                cursor, pairs);
      rp_d = rowptr;
      pr_d = pairs;
    }

    // t1 = mlp3_f(x)
    mlp3_k<0><<<GRID_MLP, 512, SMEM_TOTAL, stream>>>(x, wf, b_f1, b_f2, b_f3, t1,
                                                     nullptr, nullptr, nullptr,
                                                     nullptr);
    // out = x + mask * mlp3_f(segsum(adj * t1[dst], src))   [gather fused]
    float* outp;
    if (tier > 0)
      outp = (d == NDEPTH - 1) ? (float*)d_out : x;
    else
      outp = x;   // tiny tier: t1 aliases d_out, publish via final D2D copy
    mlp3_k<1><<<GRID_MLP, 512, SMEM_TOTAL, stream>>>(t1, wf, b_f1, b_f2, b_f3, outp,
                                                     x, masks + (size_t)d * NNODES,
                                                     pr_d, rp_d);
  }

  if (tier == 0) {
    hipMemcpyAsync(d_out, x, (size_t)NNODES * 128 * sizeof(float),
                   hipMemcpyDeviceToDevice, stream);
  }
}